// Round 17
// baseline (191.662 us; speedup 1.0000x reference)
//
#include <hip/hip_runtime.h>

// stimuli [4,32,304,608,1] fp32, eye [4,32,2,3] fp32
#define BH 304
#define BW 608
#define BHW (BH * BW)     // 184832 = 512 * 361
#define NFRAMES 128

typedef float vf2 __attribute__((ext_vector_type(2)));

// 256 thr/block, 2 CONSECUTIVE px per lane -> dwordx2 stores (0.5 addr/px).
// Gathers exec-masked to the ~31% valid region (exact-zero elsewhere, proven
// R6/R7/R16); dead px skip all lerp/address VALU. Odd-px coords via +Ax delta
// (R10-proven). Block covers 512 consecutive px (<=2 rows; pairs never split
// rows since BW and all offsets are even).
__global__ __launch_bounds__(256) void warp_bilinear_pair2_kernel(
    const float* __restrict__ stimuli,
    const float* __restrict__ eye,
    float* __restrict__ out)
{
    const int n    = blockIdx.y;            // frame (wave-uniform)
    const int base = blockIdx.x * 512;      // block's first pixel (uniform)
    const int py0  = base / BW;             // uniform -> SALU
    const int pc0  = base - py0 * BW;       // even

    const float* aff = eye + n * 6;
    const double a00 = aff[0], a01 = aff[1], a02 = aff[2];
    const double a10 = aff[3], a11 = aff[4], a12 = aff[5];

    const double yy0 = -1.0 + 2.0 * (double)py0       / (double)(BH - 1);
    const double yy1 = -1.0 + 2.0 * (double)(py0 + 1) / (double)(BH - 1);

    const float Ax  = (float)(a00 * (2.0 / (double)(BW - 1)) * (0.5 * (double)BW));
    const float Ay  = (float)(a10 * (2.0 / (double)(BW - 1)) * (0.5 * (double)BH));
    const float Bx0 = (float)((a01 * yy0 + a02 + 1.0 - a00) * (0.5 * (double)BW));
    const float Bx1 = (float)((a01 * yy1 + a02 + 1.0 - a00) * (0.5 * (double)BW));
    const float By0 = (float)((a11 * yy0 + a12 + 1.0 - a10) * (0.5 * (double)BH));
    const float By1 = (float)((a11 * yy1 + a12 + 1.0 - a10) * (0.5 * (double)BH));

    const float* __restrict__ img = stimuli + (size_t)n * BHW;

    // pair of consecutive pixels; off is even, pair never straddles a row
    const int off  = pc0 + 2 * (int)threadIdx.x;     // < 2*BW
    const bool wrap = (off >= BW);
    const float pxf = (float)(wrap ? off - BW : off);

    const float xe = fmaf(Ax, pxf, wrap ? Bx1 : Bx0);
    const float ye = fmaf(Ay, pxf, wrap ? By1 : By0);
    const float xo = xe + Ax;               // odd pixel via uniform delta (R10-proven)
    const float yo = ye + Ay;

    float res2[2];
    const float xs[2] = {xe, xo};
    const float ys[2] = {ye, yo};

    #pragma unroll
    for (int k = 0; k < 2; ++k) {
        const float x = xs[k], y = ys[k];
        const float x0f = floorf(x);
        const float y0f = floorf(y);
        const int x0 = (int)x0f;
        const int y0 = (int)y0f;

        const bool v = ((unsigned)x0 < (unsigned)(BW - 1)) &
                       ((unsigned)y0 < (unsigned)(BH - 1));

        float r = 0.0f;
        if (v) {
            // in-bounds by construction: x0 in [0,606], y0 in [0,302]
            const float* rp = img + y0 * BW + x0;
            vf2 va, vb;
            __builtin_memcpy(&va, rp, 8);          // row y0: [x0, x0+1]
            __builtin_memcpy(&vb, rp + BW, 8);     // row y0+1, same addr + imm
            const float fx = x - x0f;
            const float fy = y - y0f;
            const float ix0 = va.x + fx * (va.y - va.x);
            const float ix1 = vb.x + fx * (vb.y - vb.x);
            r = ix0 + fy * (ix1 - ix0);
        }
        res2[k] = r;
    }

    vf2 res; res.x = res2[0]; res.y = res2[1];
    __builtin_memcpy(out + (size_t)n * BHW + base + 2 * (int)threadIdx.x, &res, 8);
}

extern "C" void kernel_launch(void* const* d_in, const int* in_sizes, int n_in,
                              void* d_out, int out_size, void* d_ws, size_t ws_size,
                              hipStream_t stream) {
    const float* stimuli = (const float*)d_in[0];
    const float* eye     = (const float*)d_in[1];
    float* out = (float*)d_out;

    dim3 grid(BHW / 512, NFRAMES);   // 361 x 128
    dim3 block(256);
    warp_bilinear_pair2_kernel<<<grid, block, 0, stream>>>(stimuli, eye, out);
}